// Round 8
// baseline (129.500 us; speedup 1.0000x reference)
//
#include <hip/hip_runtime.h>

#define NBINS 128
#define NB2   (NBINS * NBINS)
#define TPB   256             // 4 waves/block, 1 wave/SIMD (VGPR-bound)
#define NBLK  256             // 1 block/CU
#define KC    64              // points per chunk

typedef __attribute__((ext_vector_type(8)))  short short8;
typedef __attribute__((ext_vector_type(16))) float f32x16;

// pack two fp32 -> two bf16 (round-half-up, <=0.5ulp) in one v_perm
__device__ __forceinline__ unsigned pk_bf16(float a, float b) {
    const unsigned ar = __float_as_uint(a) + 0x8000u;
    const unsigned br = __float_as_uint(b) + 0x8000u;
    return __builtin_amdgcn_perm(br, ar, 0x07060302u);
}

// weight(d) = exp(-0.5 d^2) = exp2(WC d^2), WC = -0.5*log2(e)
#define WC (-0.72134752044448170f)

union S8 { short8 s; unsigned u[4]; };

// gen one 32-wide tile fragment: elem j = w(vals[j] - base), vals from float4s
__device__ __forceinline__ S8 gen_frag(const float4 a, const float4 b, float base) {
    float d0 = a.x - base, d1 = a.y - base, d2 = a.z - base, d3 = a.w - base;
    float d4 = b.x - base, d5 = b.y - base, d6 = b.z - base, d7 = b.w - base;
    const float w0 = __builtin_amdgcn_exp2f((WC * d0) * d0);
    const float w1 = __builtin_amdgcn_exp2f((WC * d1) * d1);
    const float w2 = __builtin_amdgcn_exp2f((WC * d2) * d2);
    const float w3 = __builtin_amdgcn_exp2f((WC * d3) * d3);
    const float w4 = __builtin_amdgcn_exp2f((WC * d4) * d4);
    const float w5 = __builtin_amdgcn_exp2f((WC * d5) * d5);
    const float w6 = __builtin_amdgcn_exp2f((WC * d6) * d6);
    const float w7 = __builtin_amdgcn_exp2f((WC * d7) * d7);
    S8 r;
    r.u[0] = pk_bf16(w0, w1); r.u[1] = pk_bf16(w2, w3);
    r.u[2] = pk_bf16(w4, w5); r.u[3] = pk_bf16(w6, w7);
    return r;
}

// Single fused kernel: hist = kx^T * ky as 128x128xK bf16 MFMA GEMM (dense
// taps). Each WAVE owns the full 128x128 grid (16 acc tiles of 32x32) and a
// private chunk stream -> fragment exps amortize over 16 MFMAs (R7's
// quadrant scheme recomputed every exp 2x; trans issue @~16cyc/wave was 64%
// of k1). Wave-private LDS staging slot: same-wave ds_write->ds_read needs
// only lgkmcnt, NO barriers in the K-loop -> 1 wave/SIMD is fine.
// Epilogue: 2-phase LDS merge of the 4 waves, global atomic add into out,
// then last-block total+normalize (folds the old k2 dispatch away).
__global__ __launch_bounds__(TPB, 1) void kde_mfma_kernel(
    const float* __restrict__ x,
    const float* __restrict__ ex,
    const float* __restrict__ ey,
    float* __restrict__ out,
    unsigned* __restrict__ counter,
    int n, int nchunks)
{
    __shared__ float hist[NB2];                       // 64 KB
    __shared__ float hist2[NB2];                      // 64 KB
    __shared__ __align__(16) float u_s[4][KC];        // per-wave slots
    __shared__ __align__(16) float v_s[4][KC];
    __shared__ float redbuf[4];
    __shared__ int   lastflag;

    const int tid  = (int)threadIdx.x;
    const int lane = tid & 63;
    const int half = lane >> 5;
    const int l31  = lane & 31;
    const int wave = tid >> 6;
    const float l31f = (float)l31;

    const float lox = ex[0], loy = ey[0];
    const float ibx = 1.0f / (ex[1] - ex[0]);
    const float iby = 1.0f / (ey[1] - ey[0]);

    f32x16 acc[4][4];
    #pragma unroll
    for (int a = 0; a < 4; ++a)
        #pragma unroll
        for (int c = 0; c < 4; ++c)
            #pragma unroll
            for (int r = 0; r < 16; ++r) acc[a][c][r] = 0.f;

    const int gstep = NBLK * 4;
    int g = (int)blockIdx.x * 4 + wave;

    // prefetch chunk g's point for this lane (u = (x-lo)/bw - 0.5; pad 1e9
    // gives exp2(-7e17) = 0 weights, no overflow)
    float uu = 1e9f, vv = 1e9f;
    {
        const int p = g * KC + lane;
        if (g < nchunks && p < n) {
            const float2 xy = *(const float2*)(x + (size_t)p * 6);
            uu = (xy.x - lox) * ibx - 0.5f;
            vv = (xy.y - loy) * iby - 0.5f;
        }
    }

    for (; g < nchunks; g += gstep) {
        // stage current chunk into this wave's private slot (no barrier:
        // same-wave LDS RAW is ordered by lgkmcnt, compiler inserts it)
        u_s[wave][lane] = uu; v_s[wave][lane] = vv;

        // prefetch next chunk during compute
        const int gn = g + gstep;
        uu = 1e9f; vv = 1e9f;
        if (gn < nchunks) {
            const int p = gn * KC + lane;
            if (p < n) {
                const float2 xy = *(const float2*)(x + (size_t)p * 6);
                uu = (xy.x - lox) * ibx - 0.5f;
                vv = (xy.y - loy) * iby - 0.5f;
            }
        }

        #pragma unroll
        for (int s4 = 0; s4 < 4; ++s4) {              // 4 k-steps of 16 pts
            const int kb = s4 * 16 + half * 8;
            const float4 ua = *(const float4*)&u_s[wave][kb];
            const float4 ub = *(const float4*)&u_s[wave][kb + 4];
            const float4 va = *(const float4*)&v_s[wave][kb];
            const float4 vb = *(const float4*)&v_s[wave][kb + 4];

            S8 af[4], bf[4];
            #pragma unroll
            for (int t = 0; t < 4; ++t) {
                af[t] = gen_frag(ua, ub, l31f + (float)(t * 32));
                bf[t] = gen_frag(va, vb, l31f + (float)(t * 32));
            }
            #pragma unroll
            for (int rt = 0; rt < 4; ++rt)
                #pragma unroll
                for (int ct = 0; ct < 4; ++ct)
                    acc[rt][ct] = __builtin_amdgcn_mfma_f32_32x32x16_bf16(
                        af[rt].s, bf[ct].s, acc[rt][ct], 0, 0, 0);
        }
    }

    // ---- merge 4 waves' full-grid accumulators ----
    // C/D layout (verified R6/R7): row=(r&3)+8*(r>>2)+4*half (+32*rt), col=l31+32*ct
    __syncthreads();   // staging slots dead; hist[] reuse safe
    #pragma unroll
    for (int ph = 0; ph < 2; ++ph) {
        if ((wave & 1) == ph) {
            float* hb = (wave >> 1) ? hist2 : hist;
            #pragma unroll
            for (int rt = 0; rt < 4; ++rt)
                #pragma unroll
                for (int ct = 0; ct < 4; ++ct)
                    #pragma unroll
                    for (int r = 0; r < 16; ++r) {
                        const int row = rt * 32 + (r & 3) + 8 * (r >> 2) + 4 * half;
                        const int a = row * NBINS + ct * 32 + l31;
                        if (ph == 0) hb[a] = acc[rt][ct][r];
                        else         hb[a] += acc[rt][ct][r];
                    }
        }
        __syncthreads();
    }

    // device-scope atomic merge into out (memset-zeroed host-side)
    for (int i = tid; i < NB2; i += TPB)
        unsafeAtomicAdd(&out[i], hist[i] + hist2[i]);

    // ---- last-block finalize (folds old kernel 2) ----
    __threadfence();                 // release our atomics
    __syncthreads();
    if (tid == 0) {
        const unsigned old = __hip_atomic_fetch_add(
            counter, 1u, __ATOMIC_ACQ_REL, __HIP_MEMORY_SCOPE_AGENT);
        lastflag = (old == (unsigned)(NBLK - 1));
    }
    __syncthreads();
    if (lastflag) {
        __threadfence();             // acquire for all threads of this block
        float4 vals[16];
        float s = 0.f;
        #pragma unroll
        for (int k = 0; k < 16; ++k) {
            vals[k] = ((const float4*)out)[tid + k * TPB];
            s += vals[k].x + vals[k].y + vals[k].z + vals[k].w;
        }
        #pragma unroll
        for (int off = 32; off > 0; off >>= 1) s += __shfl_down(s, off, 64);
        if (lane == 0) redbuf[wave] = s;
        __syncthreads();
        const float tot = redbuf[0] + redbuf[1] + redbuf[2] + redbuf[3];
        const float inv = 1.0f / (tot * (ex[1] - ex[0]) * (ey[1] - ey[0]));
        #pragma unroll
        for (int k = 0; k < 16; ++k) {
            float4 o = vals[k];
            o.x *= inv; o.y *= inv; o.z *= inv; o.w *= inv;
            ((float4*)out)[tid + k * TPB] = o;
        }
    }
}

extern "C" void kernel_launch(void* const* d_in, const int* in_sizes, int n_in,
                              void* d_out, int out_size, void* d_ws, size_t ws_size,
                              hipStream_t stream)
{
    const float* x  = (const float*)d_in[0];
    const float* ex = (const float*)d_in[1];
    const float* ey = (const float*)d_in[2];
    float* out = (float*)d_out;
    const int n = in_sizes[0] / 6;
    const int nchunks = (n + KC - 1) / KC;

    hipMemsetAsync(d_out, 0, NB2 * sizeof(float), stream);  // atomic target
    hipMemsetAsync(d_ws, 0, 64, stream);                    // done-counter
    kde_mfma_kernel<<<NBLK, TPB, 0, stream>>>(
        x, ex, ey, out, (unsigned*)d_ws, n, nchunks);
}